// Round 4
// baseline (485.899 us; speedup 1.0000x reference)
//
#include <hip/hip_runtime.h>

// ColorDenseCRFLoss via MFMA + triangle symmetry:
// out = -1e-7/4 * sum_{n,p,q} exp(-0.5*||f_p-f_q||^2) * (seg_p . seg_q)
//     = -1e-7/4 * sum_n (2*sum_{tilepairs t1<t2} + sum_{t1==t2})
// Both inner products via mfma_f32_16x16x32_bf16 on augmented per-pixel
// bf16 vectors (hi/lo split => ~fp32 product precision).

#define N_BATCH 4
#define IH 128
#define IW 128
#define P 4096   // 64x64 downsampled pixels per batch
#define KC 21

using short8  = __attribute__((ext_vector_type(8))) short;
using floatx4 = __attribute__((ext_vector_type(4))) float;

static constexpr float INV_SIGMA = 1.0f / 15.0f;
static constexpr float LOG2E     = 1.4426950408889634f;
static constexpr float OUT_SCALE = -1e-7f / 4.0f;

// ws layout (bytes):
//   [0,64)      zero page (16B used, read by padded quads)
//   argA: N*P rows x 16 bf16 (32B each)
//   argB: N*P rows x 16 bf16 (32B each)
//   seg : N*P rows x 24 bf16 (48B each)
#define ZP_OFF   0
#define ARGA_OFF 64
#define ARGB_OFF (ARGA_OFF + N_BATCH * P * 32)
#define SEG_OFF  (ARGB_OFF + N_BATCH * P * 32)

#define NFEAT (N_BATCH * P)          // 16384 feats/args threads
#define NSEG  (N_BATCH * KC * P)     // 344064 seg-pool threads

__device__ __forceinline__ ushort f2bf(float x) {  // RNE float->bf16 bits
    unsigned u = __builtin_bit_cast(unsigned, x);
    unsigned r = (u + 0x7FFFu + ((u >> 16) & 1u)) >> 16;
    return (ushort)r;
}
__device__ __forceinline__ float bf2f(ushort h) {
    return __builtin_bit_cast(float, (unsigned)h << 16);
}

// Parallel prep: threads [0,NFEAT) build per-pixel arg vectors (and zero the
// seg pad + zero page + out); threads [NFEAT, NFEAT+NSEG) each pool ONE
// (batch, channel, pixel) -> one bf16 store.
__global__ void crf_prep(const float* __restrict__ img,
                         const float* __restrict__ seg,
                         char* __restrict__ wsb,
                         float* __restrict__ out)
{
    int t = blockIdx.x * blockDim.x + threadIdx.x;
    if (t < NFEAT) {
        if (t == 0) out[0] = 0.0f;
        if (t < 16) ((float*)(wsb + ZP_OFF))[t] = 0.0f;  // zero page

        int n = t >> 12;
        int p = t & (P - 1);
        int y = p >> 6, x = p & 63;

        const float* ib = img + (size_t)n * 3 * IH * IW + (size_t)(2 * y) * IW + 2 * x;
        float f0 = ib[0] * INV_SIGMA;
        float f1 = ib[IH * IW] * INV_SIGMA;
        float f2 = ib[2 * IH * IW] * INV_SIGMA;
        float h = 0.5f * (f0 * f0 + f1 * f1 + f2 * f2);

        // A-side color, pre-scaled by log2(e); hi/lo bf16 split
        float fa0 = f0 * LOG2E, fa1 = f1 * LOG2E, fa2 = f2 * LOG2E;
        ushort ah0 = f2bf(fa0), ah1 = f2bf(fa1), ah2 = f2bf(fa2);
        ushort al0 = f2bf(fa0 - bf2f(ah0));
        ushort al1 = f2bf(fa1 - bf2f(ah1));
        ushort al2 = f2bf(fa2 - bf2f(ah2));
        float nhL = -h * LOG2E;
        ushort nhh = f2bf(nhL), nhl = f2bf(nhL - bf2f(nhh));
        // B-side color, unscaled; hi/lo split
        ushort bh0 = f2bf(f0), bh1 = f2bf(f1), bh2 = f2bf(f2);
        ushort bl0 = f2bf(f0 - bf2f(bh0));
        ushort bl1 = f2bf(f1 - bf2f(bh1));
        ushort bl2 = f2bf(f2 - bf2f(bh2));
        float hL = h * LOG2E;
        ushort hbh = f2bf(hL), hbl = f2bf(hL - bf2f(hbh));

        const ushort ONE = 0x3F80, NEG1 = 0xBF80;
        // dot(argA_p, argB_q) = log2e * (f_p.f_q - h_p - h_q)
        ushort rA[16] = {ah0, ah1, ah2, ah0, ah1, ah2, al0, al1, al2, al0, al1, al2,
                         nhh, nhl, NEG1, NEG1};
        ushort rB[16] = {bh0, bh1, bh2, bl0, bl1, bl2, bh0, bh1, bh2, bl0, bl1, bl2,
                         ONE, ONE, hbh, hbl};

        short8 vA0, vA1, vB0, vB1;
#pragma unroll
        for (int j = 0; j < 8; ++j) {
            vA0[j] = (short)rA[j];     vA1[j] = (short)rA[8 + j];
            vB0[j] = (short)rB[j];     vB1[j] = (short)rB[8 + j];
        }
        short8* dA = (short8*)(wsb + ARGA_OFF + (size_t)t * 32);
        dA[0] = vA0; dA[1] = vA1;
        short8* dB = (short8*)(wsb + ARGB_OFF + (size_t)t * 32);
        dB[0] = vB0; dB[1] = vB1;

        // zero the seg pad (k = 21..23) for this pixel
        char* sp = wsb + SEG_OFF + (size_t)t * 48;
        *(ushort*)(sp + 42) = 0;
        *(uint*)(sp + 44) = 0;
    } else if (t < NFEAT + NSEG) {
        int u = t - NFEAT;           // ((n*21 + k) << 12) | p
        int p = u & (P - 1);
        int nk = u >> 12;            // n*21 + k
        int n = nk / 21;
        int k = nk - n * 21;
        int y = p >> 6, x = p & 63;

        const float* s = seg + (size_t)nk * IH * IW + (size_t)(2 * y) * IW + 2 * x;
        float v = 0.25f * ((s[0] + s[1]) + (s[IW] + s[IW + 1]));
        *(ushort*)(wsb + SEG_OFF + (size_t)(n * P + p) * 48 + k * 2) = f2bf(v);
    }
}

// Upper-triangle tile enumeration. Block bp pairs strip bp with strip 63-bp
// (a strip = 4 consecutive 16-row i-tiles). Strip bs streams j-tiles
// [4*bs, 256): counts c0 = 256-4bp and c1 = 4+4bp, total 260 items/block
// for every bp (balanced). 32-way split of items across 8 x-blocks * 4 waves.
// Off-diagonal tiles weight 2 (acc2), diagonal tiles weight 1 (acc1).
__global__ __launch_bounds__(256) void crf_pair(const char* __restrict__ wsb,
                                                float* __restrict__ out)
{
    int n = blockIdx.z;
    int bp = blockIdx.y;             // [0,32)
    int wave = threadIdx.x >> 6;
    int lane = threadIdx.x & 63;
    int quad = lane >> 4;
    int l16  = lane & 15;

    const char* argA = wsb + ARGA_OFF + (size_t)n * P * 32;
    const char* argB = wsb + ARGB_OFF + (size_t)n * P * 32;
    const char* segT = wsb + SEG_OFF  + (size_t)n * P * 48;
    const char* zp   = wsb + ZP_OFF;

    int s0 = 4 * bp;                 // strip0 first i-tile
    int s1 = 4 * (63 - bp);          // strip1 first i-tile
    int c0 = 256 - s0;               // strip0 item count (total items = 260)

    // A fragments: frags 0..3 = strip0 i-tiles, 4..7 = strip1 i-tiles
    short8 aArg[8], aSeg[8];
#pragma unroll
    for (int ii = 0; ii < 4; ++ii) {
        int r0 = (s0 + ii) * 16 + l16;
        int r1 = (s1 + ii) * 16 + l16;
        aArg[ii]     = *(const short8*)(quad < 2 ? argA + r0 * 32 + quad * 16 : zp);
        aSeg[ii]     = *(const short8*)(quad < 3 ? segT + r0 * 48 + quad * 16 : zp);
        aArg[4 + ii] = *(const short8*)(quad < 2 ? argA + r1 * 32 + quad * 16 : zp);
        aSeg[4 + ii] = *(const short8*)(quad < 3 ? segT + r1 * 48 + quad * 16 : zp);
    }

    float acc1 = 0.0f, acc2 = 0.0f;
    int wq = blockIdx.x * 4 + wave;  // [0,32), item stride 32

    int m = wq;
    int tag = (m >= c0);
    int j = tag ? (s1 + (m - c0)) : (s0 + m);
    int qr = j * 16 + l16;
    short8 bArg = *(const short8*)(quad < 2 ? argB + qr * 32 + quad * 16 : zp);
    short8 bSeg = *(const short8*)(quad < 3 ? segT + qr * 48 + quad * 16 : zp);

    while (m < 260) {
        int mn = m + 32;
        int tagN = 0, jn = j;
        short8 bArgN = bArg, bSegN = bSeg;
        if (mn < 260) {
            tagN = (mn >= c0);
            jn = tagN ? (s1 + (mn - c0)) : (s0 + mn);
            int qn = jn * 16 + l16;
            bArgN = *(const short8*)(quad < 2 ? argB + qn * 32 + quad * 16 : zp);
            bSegN = *(const short8*)(quad < 3 ? segT + qn * 48 + quad * 16 : zp);
        }

        int base = tag ? 4 : 0;
        int it0  = tag ? s1 : s0;
        floatx4 zero = {0.0f, 0.0f, 0.0f, 0.0f};
#pragma unroll
        for (int ii = 0; ii < 4; ++ii) {
            int it = it0 + ii;
            if (it > j) continue;    // lower triangle: skip (wave-uniform)
            floatx4 g  = __builtin_amdgcn_mfma_f32_16x16x32_bf16(aSeg[base + ii], bSeg, zero, 0, 0, 0);
            floatx4 ar = __builtin_amdgcn_mfma_f32_16x16x32_bf16(aArg[base + ii], bArg, zero, 0, 0, 0);
            if (it == j) {
#pragma unroll
                for (int jj = 0; jj < 4; ++jj)
                    acc1 += __builtin_amdgcn_exp2f(ar[jj]) * g[jj];
            } else {
#pragma unroll
                for (int jj = 0; jj < 4; ++jj)
                    acc2 += __builtin_amdgcn_exp2f(ar[jj]) * g[jj];
            }
        }
        m = mn; tag = tagN; j = jn; bArg = bArgN; bSeg = bSegN;
    }

    float part = 2.0f * acc2 + acc1;
    // reduce: wave -> block -> global
#pragma unroll
    for (int off = 32; off > 0; off >>= 1)
        part += __shfl_down(part, off, 64);
    __shared__ float wsum[4];
    if (lane == 0) wsum[wave] = part;
    __syncthreads();
    if (threadIdx.x == 0)
        atomicAdd(out, ((wsum[0] + wsum[1]) + (wsum[2] + wsum[3])) * OUT_SCALE);
}

extern "C" void kernel_launch(void* const* d_in, const int* in_sizes, int n_in,
                              void* d_out, int out_size, void* d_ws, size_t ws_size,
                              hipStream_t stream)
{
    const float* images = (const float*)d_in[0];   // [4,3,128,128]
    const float* segm   = (const float*)d_in[1];   // [4,21,128,128]
    float* out = (float*)d_out;                    // [1]
    char* wsb = (char*)d_ws;                       // ~1.79 MB used

    int prep_threads = NFEAT + NSEG;
    crf_prep<<<dim3((prep_threads + 255) / 256), dim3(256), 0, stream>>>(
        images, segm, wsb, out);
    crf_pair<<<dim3(8, 32, N_BATCH), dim3(256), 0, stream>>>(wsb, out);
}

// Round 5
// 80.952 us; speedup vs baseline: 6.0024x; 6.0024x over previous
//
#include <hip/hip_runtime.h>

// ColorDenseCRFLoss via MFMA + triangle symmetry (all-static inner loops):
// out = -1e-7/4 * sum_{n,p,q} exp(-0.5*||f_p-f_q||^2) * (seg_p . seg_q)
// Tile-level: sum = 2*sum_{tile i<j} + sum_{tile i==j}. Block bp pairs strip
// bp (4 i-tiles) with strip 63-bp; main phases stream j>strip with weight 2,
// edge phases handle the 4x4 diagonal tile block with cndmask weights.
// No dynamic register-array indexing anywhere (R4 post-mortem).

#define N_BATCH 4
#define IH 128
#define IW 128
#define P 4096   // 64x64 downsampled pixels per batch
#define KC 21

using short8  = __attribute__((ext_vector_type(8))) short;
using floatx4 = __attribute__((ext_vector_type(4))) float;

static constexpr float INV_SIGMA = 1.0f / 15.0f;
static constexpr float LOG2E     = 1.4426950408889634f;
static constexpr float OUT_SCALE = -1e-7f / 4.0f;

// ws layout (bytes):
//   [0,64)  zero page; argA/argB: rows x 32B; seg: rows x 48B
#define ZP_OFF   0
#define ARGA_OFF 64
#define ARGB_OFF (ARGA_OFF + N_BATCH * P * 32)
#define SEG_OFF  (ARGB_OFF + N_BATCH * P * 32)

#define NFEAT (N_BATCH * P)          // 16384
#define NSEG  (N_BATCH * KC * P)     // 344064

__device__ __forceinline__ ushort f2bf(float x) {  // RNE float->bf16 bits
    unsigned u = __builtin_bit_cast(unsigned, x);
    unsigned r = (u + 0x7FFFu + ((u >> 16) & 1u)) >> 16;
    return (ushort)r;
}
__device__ __forceinline__ float bf2f(ushort h) {
    return __builtin_bit_cast(float, (unsigned)h << 16);
}

__global__ void crf_prep(const float* __restrict__ img,
                         const float* __restrict__ seg,
                         char* __restrict__ wsb,
                         float* __restrict__ out)
{
    int t = blockIdx.x * blockDim.x + threadIdx.x;
    if (t < NFEAT) {
        if (t == 0) out[0] = 0.0f;
        if (t < 16) ((float*)(wsb + ZP_OFF))[t] = 0.0f;  // zero page

        int n = t >> 12;
        int p = t & (P - 1);
        int y = p >> 6, x = p & 63;

        const float* ib = img + (size_t)n * 3 * IH * IW + (size_t)(2 * y) * IW + 2 * x;
        float f0 = ib[0] * INV_SIGMA;
        float f1 = ib[IH * IW] * INV_SIGMA;
        float f2 = ib[2 * IH * IW] * INV_SIGMA;
        float h = 0.5f * (f0 * f0 + f1 * f1 + f2 * f2);

        float fa0 = f0 * LOG2E, fa1 = f1 * LOG2E, fa2 = f2 * LOG2E;
        ushort ah0 = f2bf(fa0), ah1 = f2bf(fa1), ah2 = f2bf(fa2);
        ushort al0 = f2bf(fa0 - bf2f(ah0));
        ushort al1 = f2bf(fa1 - bf2f(ah1));
        ushort al2 = f2bf(fa2 - bf2f(ah2));
        float nhL = -h * LOG2E;
        ushort nhh = f2bf(nhL), nhl = f2bf(nhL - bf2f(nhh));
        ushort bh0 = f2bf(f0), bh1 = f2bf(f1), bh2 = f2bf(f2);
        ushort bl0 = f2bf(f0 - bf2f(bh0));
        ushort bl1 = f2bf(f1 - bf2f(bh1));
        ushort bl2 = f2bf(f2 - bf2f(bh2));
        float hL = h * LOG2E;
        ushort hbh = f2bf(hL), hbl = f2bf(hL - bf2f(hbh));

        const ushort ONE = 0x3F80, NEG1 = 0xBF80;
        // dot(argA_p, argB_q) = log2e * (f_p.f_q - h_p - h_q)
        ushort rA[16] = {ah0, ah1, ah2, ah0, ah1, ah2, al0, al1, al2, al0, al1, al2,
                         nhh, nhl, NEG1, NEG1};
        ushort rB[16] = {bh0, bh1, bh2, bl0, bl1, bl2, bh0, bh1, bh2, bl0, bl1, bl2,
                         ONE, ONE, hbh, hbl};

        short8 vA0, vA1, vB0, vB1;
#pragma unroll
        for (int j = 0; j < 8; ++j) {
            vA0[j] = (short)rA[j];     vA1[j] = (short)rA[8 + j];
            vB0[j] = (short)rB[j];     vB1[j] = (short)rB[8 + j];
        }
        short8* dA = (short8*)(wsb + ARGA_OFF + (size_t)t * 32);
        dA[0] = vA0; dA[1] = vA1;
        short8* dB = (short8*)(wsb + ARGB_OFF + (size_t)t * 32);
        dB[0] = vB0; dB[1] = vB1;

        char* sp = wsb + SEG_OFF + (size_t)t * 48;   // zero seg pad k=21..23
        *(ushort*)(sp + 42) = 0;
        *(uint*)(sp + 44) = 0;
    } else if (t < NFEAT + NSEG) {
        int u = t - NFEAT;
        int p = u & (P - 1);
        int nk = u >> 12;            // n*21 + k
        int n = nk / 21;
        int k = nk - n * 21;
        int y = p >> 6, x = p & 63;

        const float* s = seg + (size_t)nk * IH * IW + (size_t)(2 * y) * IW + 2 * x;
        float v = 0.25f * ((s[0] + s[1]) + (s[IW] + s[IW + 1]));
        *(ushort*)(wsb + SEG_OFF + (size_t)(n * P + p) * 48 + k * 2) = f2bf(v);
    }
}

__global__ __launch_bounds__(256) void crf_pair(const char* __restrict__ wsb,
                                                float* __restrict__ out)
{
    int n = blockIdx.z;
    int bp = blockIdx.y;             // [0,32): pairs strip bp with strip 63-bp
    int wave = threadIdx.x >> 6;
    int lane = threadIdx.x & 63;
    int quad = lane >> 4;
    int l16  = lane & 15;
    int w    = blockIdx.x * 4 + wave;   // worker id [0,32)

    const char* argA = wsb + ARGA_OFF + (size_t)n * P * 32;
    const char* argB = wsb + ARGB_OFF + (size_t)n * P * 32;
    const char* segT = wsb + SEG_OFF  + (size_t)n * P * 48;
    const char* zp   = wsb + ZP_OFF;

    // per-lane (base, stride): stride 0 routes pad lanes to the zero page
    const char* aAB = (quad < 2) ? argA + quad * 16 : zp;
    const char* bAB = (quad < 2) ? argB + quad * 16 : zp;
    const char* sB  = (quad < 3) ? segT + quad * 16 : zp;
    int aStep = (quad < 2) ? 32 : 0;
    int sStep = (quad < 3) ? 48 : 0;

    int s0 = 4 * bp;                 // strip0 first i-tile
    int s1 = 4 * (63 - bp);          // strip1 first i-tile

    // A fragments (static names, unrolled indices only)
    short8 aA0[4], aS0[4], aA1[4], aS1[4];
#pragma unroll
    for (int ii = 0; ii < 4; ++ii) {
        int r0 = (s0 + ii) * 16 + l16;
        int r1 = (s1 + ii) * 16 + l16;
        aA0[ii] = *(const short8*)(aAB + (size_t)r0 * aStep);
        aS0[ii] = *(const short8*)(sB  + (size_t)r0 * sStep);
        aA1[ii] = *(const short8*)(aAB + (size_t)r1 * aStep);
        aS1[ii] = *(const short8*)(sB  + (size_t)r1 * sStep);
    }

    float acc2 = 0.0f;   // weight-2 (strict upper triangle) sum
    float accE = 0.0f;   // edge sum (weights already applied)
    floatx4 zero = {0.0f, 0.0f, 0.0f, 0.0f};

    // ---- Main phase 0: strip0 vs j in [s0+4, 256), weight 2 ----
    {
        int cnt = 252 - s0;
        int m = w;
        if (m < cnt) {
            int j = s0 + 4 + m;
            int qr = j * 16 + l16;
            short8 bArg = *(const short8*)(bAB + (size_t)qr * aStep);
            short8 bSeg = *(const short8*)(sB  + (size_t)qr * sStep);
            while (m < cnt) {
                int mn = m + 32;
                int jn = (mn < cnt) ? s0 + 4 + mn : j;
                int qn = jn * 16 + l16;
                short8 bArgN = *(const short8*)(bAB + (size_t)qn * aStep);
                short8 bSegN = *(const short8*)(sB  + (size_t)qn * sStep);
#pragma unroll
                for (int ii = 0; ii < 4; ++ii) {
                    floatx4 g  = __builtin_amdgcn_mfma_f32_16x16x32_bf16(aS0[ii], bSeg, zero, 0, 0, 0);
                    floatx4 ar = __builtin_amdgcn_mfma_f32_16x16x32_bf16(aA0[ii], bArg, zero, 0, 0, 0);
#pragma unroll
                    for (int jj = 0; jj < 4; ++jj)
                        acc2 += __builtin_amdgcn_exp2f(ar[jj]) * g[jj];
                }
                m = mn; j = jn; bArg = bArgN; bSeg = bSegN;
            }
        }
    }

    // ---- Main phase 1: strip1 vs j in [s1+4, 256), weight 2 ----
    {
        int cnt = 4 * bp;
        int m = w;
        if (m < cnt) {
            int j = s1 + 4 + m;
            int qr = j * 16 + l16;
            short8 bArg = *(const short8*)(bAB + (size_t)qr * aStep);
            short8 bSeg = *(const short8*)(sB  + (size_t)qr * sStep);
            while (m < cnt) {
                int mn = m + 32;
                int jn = (mn < cnt) ? s1 + 4 + mn : j;
                int qn = jn * 16 + l16;
                short8 bArgN = *(const short8*)(bAB + (size_t)qn * aStep);
                short8 bSegN = *(const short8*)(sB  + (size_t)qn * sStep);
#pragma unroll
                for (int ii = 0; ii < 4; ++ii) {
                    floatx4 g  = __builtin_amdgcn_mfma_f32_16x16x32_bf16(aS1[ii], bSeg, zero, 0, 0, 0);
                    floatx4 ar = __builtin_amdgcn_mfma_f32_16x16x32_bf16(aA1[ii], bArg, zero, 0, 0, 0);
#pragma unroll
                    for (int jj = 0; jj < 4; ++jj)
                        acc2 += __builtin_amdgcn_exp2f(ar[jj]) * g[jj];
                }
                m = mn; j = jn; bArg = bArgN; bSeg = bSegN;
            }
        }
    }

    // ---- Edge phase 0: strip0 diagonal block, jrel = w (workers 0..3) ----
    if (w < 4) {
        int jrel = w;
        int qr = (s0 + jrel) * 16 + l16;
        short8 bArg = *(const short8*)(bAB + (size_t)qr * aStep);
        short8 bSeg = *(const short8*)(sB  + (size_t)qr * sStep);
#pragma unroll
        for (int ii = 0; ii < 4; ++ii) {
            floatx4 g  = __builtin_amdgcn_mfma_f32_16x16x32_bf16(aS0[ii], bSeg, zero, 0, 0, 0);
            floatx4 ar = __builtin_amdgcn_mfma_f32_16x16x32_bf16(aA0[ii], bArg, zero, 0, 0, 0);
            float t = 0.0f;
#pragma unroll
            for (int jj = 0; jj < 4; ++jj)
                t += __builtin_amdgcn_exp2f(ar[jj]) * g[jj];
            float wt = (ii < jrel) ? 2.0f : ((ii == jrel) ? 1.0f : 0.0f);
            accE += wt * t;
        }
    }

    // ---- Edge phase 1: strip1 diagonal block, jrel = w-4 (workers 4..7) ----
    if (w >= 4 && w < 8) {
        int jrel = w - 4;
        int qr = (s1 + jrel) * 16 + l16;
        short8 bArg = *(const short8*)(bAB + (size_t)qr * aStep);
        short8 bSeg = *(const short8*)(sB  + (size_t)qr * sStep);
#pragma unroll
        for (int ii = 0; ii < 4; ++ii) {
            floatx4 g  = __builtin_amdgcn_mfma_f32_16x16x32_bf16(aS1[ii], bSeg, zero, 0, 0, 0);
            floatx4 ar = __builtin_amdgcn_mfma_f32_16x16x32_bf16(aA1[ii], bArg, zero, 0, 0, 0);
            float t = 0.0f;
#pragma unroll
            for (int jj = 0; jj < 4; ++jj)
                t += __builtin_amdgcn_exp2f(ar[jj]) * g[jj];
            float wt = (ii < jrel) ? 2.0f : ((ii == jrel) ? 1.0f : 0.0f);
            accE += wt * t;
        }
    }

    float part = 2.0f * acc2 + accE;
#pragma unroll
    for (int off = 32; off > 0; off >>= 1)
        part += __shfl_down(part, off, 64);
    __shared__ float wsum[4];
    if (lane == 0) wsum[wave] = part;
    __syncthreads();
    if (threadIdx.x == 0)
        atomicAdd(out, ((wsum[0] + wsum[1]) + (wsum[2] + wsum[3])) * OUT_SCALE);
}

extern "C" void kernel_launch(void* const* d_in, const int* in_sizes, int n_in,
                              void* d_out, int out_size, void* d_ws, size_t ws_size,
                              hipStream_t stream)
{
    const float* images = (const float*)d_in[0];   // [4,3,128,128]
    const float* segm   = (const float*)d_in[1];   // [4,21,128,128]
    float* out = (float*)d_out;                    // [1]
    char* wsb = (char*)d_ws;                       // ~1.79 MB used

    int prep_threads = NFEAT + NSEG;
    crf_prep<<<dim3((prep_threads + 255) / 256), dim3(256), 0, stream>>>(
        images, segm, wsb, out);
    crf_pair<<<dim3(8, 32, N_BATCH), dim3(256), 0, stream>>>(wsb, out);
}

// Round 6
// 78.756 us; speedup vs baseline: 6.1697x; 1.0279x over previous
//
#include <hip/hip_runtime.h>

// ColorDenseCRFLoss via MFMA + triangle symmetry, latency-optimized:
// out = -1e-7/4 * sum_{n,p,q} exp(-0.5*||f_p-f_q||^2) * (seg_p . seg_q)
// Tile-level: sum = 2*sum_{tile i<j} + sum_{tile i==j}. Block bp pairs strip
// bp (4 i-tiles) with strip 63-bp; main phases stream j>strip with weight 2
// (2-deep prefetch, constant-stride 32-bit offsets), edge phases handle the
// 4x4 diagonal blocks. No dynamic register-array indexing (R4 post-mortem).

#define N_BATCH 4
#define IH 128
#define IW 128
#define P 4096   // 64x64 downsampled pixels per batch
#define KC 21

using short8  = __attribute__((ext_vector_type(8))) short;
using floatx4 = __attribute__((ext_vector_type(4))) float;

static constexpr float INV_SIGMA = 1.0f / 15.0f;
static constexpr float LOG2E     = 1.4426950408889634f;
static constexpr float OUT_SCALE = -1e-7f / 4.0f;

// ws layout (bytes):
//   [0,64)  zero page; argA/argB: rows x 32B; seg: rows x 48B
#define ZP_OFF   0
#define ARGA_OFF 64
#define ARGB_OFF (ARGA_OFF + N_BATCH * P * 32)
#define SEG_OFF  (ARGB_OFF + N_BATCH * P * 32)

#define NFEAT (N_BATCH * P)              // 16384
#define NSEG2 (N_BATCH * KC * P / 2)     // 172032 (2 pixels/thread)

__device__ __forceinline__ ushort f2bf(float x) {  // RNE float->bf16 bits
    unsigned u = __builtin_bit_cast(unsigned, x);
    unsigned r = (u + 0x7FFFu + ((u >> 16) & 1u)) >> 16;
    return (ushort)r;
}
__device__ __forceinline__ float bf2f(ushort h) {
    return __builtin_bit_cast(float, (unsigned)h << 16);
}

__global__ void crf_prep(const float* __restrict__ img,
                         const float* __restrict__ seg,
                         char* __restrict__ wsb,
                         float* __restrict__ out)
{
    int t = blockIdx.x * blockDim.x + threadIdx.x;
    if (t < NFEAT) {
        if (t == 0) out[0] = 0.0f;
        if (t < 16) ((float*)(wsb + ZP_OFF))[t] = 0.0f;  // zero page

        int n = t >> 12;
        int p = t & (P - 1);
        int y = p >> 6, x = p & 63;

        const float* ib = img + (size_t)n * 3 * IH * IW + (size_t)(2 * y) * IW + 2 * x;
        float f0 = ib[0] * INV_SIGMA;
        float f1 = ib[IH * IW] * INV_SIGMA;
        float f2 = ib[2 * IH * IW] * INV_SIGMA;
        float h = 0.5f * (f0 * f0 + f1 * f1 + f2 * f2);

        float fa0 = f0 * LOG2E, fa1 = f1 * LOG2E, fa2 = f2 * LOG2E;
        ushort ah0 = f2bf(fa0), ah1 = f2bf(fa1), ah2 = f2bf(fa2);
        ushort al0 = f2bf(fa0 - bf2f(ah0));
        ushort al1 = f2bf(fa1 - bf2f(ah1));
        ushort al2 = f2bf(fa2 - bf2f(ah2));
        float nhL = -h * LOG2E;
        ushort nhh = f2bf(nhL), nhl = f2bf(nhL - bf2f(nhh));
        ushort bh0 = f2bf(f0), bh1 = f2bf(f1), bh2 = f2bf(f2);
        ushort bl0 = f2bf(f0 - bf2f(bh0));
        ushort bl1 = f2bf(f1 - bf2f(bh1));
        ushort bl2 = f2bf(f2 - bf2f(bh2));
        float hL = h * LOG2E;
        ushort hbh = f2bf(hL), hbl = f2bf(hL - bf2f(hbh));

        const ushort ONE = 0x3F80, NEG1 = 0xBF80;
        // dot(argA_p, argB_q) = log2e * (f_p.f_q - h_p - h_q)
        ushort rA[16] = {ah0, ah1, ah2, ah0, ah1, ah2, al0, al1, al2, al0, al1, al2,
                         nhh, nhl, NEG1, NEG1};
        ushort rB[16] = {bh0, bh1, bh2, bl0, bl1, bl2, bh0, bh1, bh2, bl0, bl1, bl2,
                         ONE, ONE, hbh, hbl};

        short8 vA0, vA1, vB0, vB1;
#pragma unroll
        for (int j = 0; j < 8; ++j) {
            vA0[j] = (short)rA[j];     vA1[j] = (short)rA[8 + j];
            vB0[j] = (short)rB[j];     vB1[j] = (short)rB[8 + j];
        }
        short8* dA = (short8*)(wsb + ARGA_OFF + (size_t)t * 32);
        dA[0] = vA0; dA[1] = vA1;
        short8* dB = (short8*)(wsb + ARGB_OFF + (size_t)t * 32);
        dB[0] = vB0; dB[1] = vB1;

        char* sp = wsb + SEG_OFF + (size_t)t * 48;   // zero seg pad k=21..23
        *(ushort*)(sp + 42) = 0;
        *(uint*)(sp + 44) = 0;
    } else if (t < NFEAT + NSEG2) {
        int u = t - NFEAT;
        int pp = (u & 2047) * 2;     // pixel pair base (even)
        int nk = u >> 11;            // n*21 + k
        int n = nk / 21;
        int k = nk - n * 21;
        int y = pp >> 6, x0 = pp & 63;

        const float* r0 = seg + (size_t)nk * IH * IW + (size_t)(2 * y) * IW + 2 * x0;
        float4 a = *(const float4*)r0;
        float4 b = *(const float4*)(r0 + IW);
        float v0 = 0.25f * ((a.x + a.y) + (b.x + b.y));
        float v1 = 0.25f * ((a.z + a.w) + (b.z + b.w));
        char* d = wsb + SEG_OFF + (size_t)(n * P + pp) * 48 + k * 2;
        *(ushort*)d = f2bf(v0);
        *(ushort*)(d + 48) = f2bf(v1);
    }
}

__global__ __launch_bounds__(256, 4) void crf_pair(const char* __restrict__ wsb,
                                                   float* __restrict__ out)
{
    int n = blockIdx.z;
    int bp = blockIdx.y;             // [0,32): pairs strip bp with strip 63-bp
    int wave = threadIdx.x >> 6;
    int lane = threadIdx.x & 63;
    int quad = lane >> 4;
    int l16  = lane & 15;
    int w    = blockIdx.x * 4 + wave;   // worker id [0,32)

    const char* argA = wsb + ARGA_OFF + (size_t)n * P * 32;
    const char* argB = wsb + ARGB_OFF + (size_t)n * P * 32;
    const char* segT = wsb + SEG_OFF  + (size_t)n * P * 48;
    const char* zp   = wsb + ZP_OFF;

    // per-lane base + masked 32-bit offsets (mask 0 routes pads to zero page)
    int maskA = (quad < 2) ? ~0 : 0;
    int maskS = (quad < 3) ? ~0 : 0;
    const char* baseA_arg = (quad < 2) ? argA + quad * 16 : zp;
    const char* baseB_arg = (quad < 2) ? argB + quad * 16 : zp;
    const char* base_seg  = (quad < 3) ? segT + quad * 16 : zp;
    const int dA = 16384 & maskA;    // 32 rows * 16 rows/tile... = 32*16*32B
    const int dS = 24576 & maskS;    // 32*16*48B

    int s0 = 4 * bp;                 // strip0 first i-tile
    int s1 = 4 * (63 - bp);          // strip1 first i-tile

    // A fragments (static names, unrolled indices only)
    short8 aA0[4], aS0[4], aA1[4], aS1[4];
#pragma unroll
    for (int ii = 0; ii < 4; ++ii) {
        int r0 = (s0 + ii) * 16 + l16;
        int r1 = (s1 + ii) * 16 + l16;
        aA0[ii] = *(const short8*)(baseA_arg + ((r0 << 5) & maskA));
        aS0[ii] = *(const short8*)(base_seg  + ((r0 * 48) & maskS));
        aA1[ii] = *(const short8*)(baseA_arg + ((r1 << 5) & maskA));
        aS1[ii] = *(const short8*)(base_seg  + ((r1 * 48) & maskS));
    }

    float acc2 = 0.0f;   // weight-2 (strict upper triangle) sum
    float accE = 0.0f;   // edge sum (weights already applied)
    floatx4 zero = {0.0f, 0.0f, 0.0f, 0.0f};

    // ---- Main phase 0: strip0 vs j in [s0+4, 256), weight 2 ----
    {
        int cnt = 252 - s0;
        if (w < cnt) {
            int j = s0 + 4 + w;
            int r = (j << 4) + l16;
            int offA = (r << 5) & maskA;
            int offS = (r * 48) & maskS;
            int iters = ((cnt - w) + 31) >> 5;
            short8 b0a = *(const short8*)(baseB_arg + offA);
            short8 b0s = *(const short8*)(base_seg + offS);
            short8 b1a = b0a, b1s = b0s;
            if (iters > 1) {
                offA += dA; offS += dS;
                b1a = *(const short8*)(baseB_arg + offA);
                b1s = *(const short8*)(base_seg + offS);
            }
            for (int it = 0; it < iters; ++it) {
                short8 b2a = b0a, b2s = b0s;
                if (it + 2 < iters) {
                    offA += dA; offS += dS;
                    b2a = *(const short8*)(baseB_arg + offA);
                    b2s = *(const short8*)(base_seg + offS);
                }
#pragma unroll
                for (int ii = 0; ii < 4; ++ii) {
                    floatx4 g  = __builtin_amdgcn_mfma_f32_16x16x32_bf16(aS0[ii], b0s, zero, 0, 0, 0);
                    floatx4 ar = __builtin_amdgcn_mfma_f32_16x16x32_bf16(aA0[ii], b0a, zero, 0, 0, 0);
#pragma unroll
                    for (int jj = 0; jj < 4; ++jj)
                        acc2 += __builtin_amdgcn_exp2f(ar[jj]) * g[jj];
                }
                b0a = b1a; b0s = b1s; b1a = b2a; b1s = b2s;
            }
        }
    }

    // ---- Main phase 1: strip1 vs j in [s1+4, 256), weight 2 ----
    {
        int cnt = 4 * bp;
        if (w < cnt) {
            int j = s1 + 4 + w;
            int r = (j << 4) + l16;
            int offA = (r << 5) & maskA;
            int offS = (r * 48) & maskS;
            int iters = ((cnt - w) + 31) >> 5;
            short8 b0a = *(const short8*)(baseB_arg + offA);
            short8 b0s = *(const short8*)(base_seg + offS);
            short8 b1a = b0a, b1s = b0s;
            if (iters > 1) {
                offA += dA; offS += dS;
                b1a = *(const short8*)(baseB_arg + offA);
                b1s = *(const short8*)(base_seg + offS);
            }
            for (int it = 0; it < iters; ++it) {
                short8 b2a = b0a, b2s = b0s;
                if (it + 2 < iters) {
                    offA += dA; offS += dS;
                    b2a = *(const short8*)(baseB_arg + offA);
                    b2s = *(const short8*)(base_seg + offS);
                }
#pragma unroll
                for (int ii = 0; ii < 4; ++ii) {
                    floatx4 g  = __builtin_amdgcn_mfma_f32_16x16x32_bf16(aS1[ii], b0s, zero, 0, 0, 0);
                    floatx4 ar = __builtin_amdgcn_mfma_f32_16x16x32_bf16(aA1[ii], b0a, zero, 0, 0, 0);
#pragma unroll
                    for (int jj = 0; jj < 4; ++jj)
                        acc2 += __builtin_amdgcn_exp2f(ar[jj]) * g[jj];
                }
                b0a = b1a; b0s = b1s; b1a = b2a; b1s = b2s;
            }
        }
    }

    // ---- Edge phase 0: strip0 diagonal block, jrel = w (workers 0..3) ----
    if (w < 4) {
        int jrel = w;
        int r = ((s0 + jrel) << 4) + l16;
        short8 bArg = *(const short8*)(baseB_arg + ((r << 5) & maskA));
        short8 bSeg = *(const short8*)(base_seg  + ((r * 48) & maskS));
#pragma unroll
        for (int ii = 0; ii < 4; ++ii) {
            floatx4 g  = __builtin_amdgcn_mfma_f32_16x16x32_bf16(aS0[ii], bSeg, zero, 0, 0, 0);
            floatx4 ar = __builtin_amdgcn_mfma_f32_16x16x32_bf16(aA0[ii], bArg, zero, 0, 0, 0);
            float t = 0.0f;
#pragma unroll
            for (int jj = 0; jj < 4; ++jj)
                t += __builtin_amdgcn_exp2f(ar[jj]) * g[jj];
            float wt = (ii < jrel) ? 2.0f : ((ii == jrel) ? 1.0f : 0.0f);
            accE += wt * t;
        }
    }

    // ---- Edge phase 1: strip1 diagonal block, jrel = w-4 (workers 4..7) ----
    if (w >= 4 && w < 8) {
        int jrel = w - 4;
        int r = ((s1 + jrel) << 4) + l16;
        short8 bArg = *(const short8*)(baseB_arg + ((r << 5) & maskA));
        short8 bSeg = *(const short8*)(base_seg  + ((r * 48) & maskS));
#pragma unroll
        for (int ii = 0; ii < 4; ++ii) {
            floatx4 g  = __builtin_amdgcn_mfma_f32_16x16x32_bf16(aS1[ii], bSeg, zero, 0, 0, 0);
            floatx4 ar = __builtin_amdgcn_mfma_f32_16x16x32_bf16(aA1[ii], bArg, zero, 0, 0, 0);
            float t = 0.0f;
#pragma unroll
            for (int jj = 0; jj < 4; ++jj)
                t += __builtin_amdgcn_exp2f(ar[jj]) * g[jj];
            float wt = (ii < jrel) ? 2.0f : ((ii == jrel) ? 1.0f : 0.0f);
            accE += wt * t;
        }
    }

    float part = 2.0f * acc2 + accE;
#pragma unroll
    for (int off = 32; off > 0; off >>= 1)
        part += __shfl_down(part, off, 64);
    __shared__ float wsum[4];
    if (lane == 0) wsum[wave] = part;
    __syncthreads();
    if (threadIdx.x == 0)
        atomicAdd(out, ((wsum[0] + wsum[1]) + (wsum[2] + wsum[3])) * OUT_SCALE);
}

extern "C" void kernel_launch(void* const* d_in, const int* in_sizes, int n_in,
                              void* d_out, int out_size, void* d_ws, size_t ws_size,
                              hipStream_t stream)
{
    const float* images = (const float*)d_in[0];   // [4,3,128,128]
    const float* segm   = (const float*)d_in[1];   // [4,21,128,128]
    float* out = (float*)d_out;                    // [1]
    char* wsb = (char*)d_ws;                       // ~1.79 MB used

    int prep_threads = NFEAT + NSEG2;
    crf_prep<<<dim3((prep_threads + 255) / 256), dim3(256), 0, stream>>>(
        images, segm, wsb, out);
    crf_pair<<<dim3(8, 32, N_BATCH), dim3(256), 0, stream>>>(wsb, out);
}